// Round 3
// baseline (126.322 us; speedup 1.0000x reference)
//
#include <hip/hip_runtime.h>
#include <hip/hip_bf16.h>
#include <math.h>

// Problem: B=2, N=8192, M=8192, C=3, k=20; MLP 20->256->128->1 with BN+ReLU, sigmoid.
// Pipeline:
//   k_prep  : y -> pair-packed SoA planes (A=(y0a,y0b,y1a,y1b), B=(y2a,y2b,-wa,-wb))
//             + W2 transpose, fused in one launch.
//   k_knn   : per-row top-20 LARGEST pd = 2x.y - xx - yy. One wave per row.
//             Packed-f32 distance (2 cand/instr), per-lane sorted top-4
//             (3 med3 + 1 max per cand), 20-round cross-lane max-merge.
//             Exactness guard: if any lane pops all 4 slots, redo row with
//             per-lane top-20 chain (provably exact; ~1.5% of rows).
//   k_mlp1  : h1[row][256] = relu(bn1(W1 . feat))
//   k_mlp2  : GEMM [16384x256]@[256x128] + bn2 + relu + W3 dot, fused
//   k_out   : sigmoid(p0+p1)

#define M_CAND 8192
#define NROWS 16384
#define KSEL 20
#define MPL 4            // per-lane list length (main path)

typedef float v2f __attribute__((ext_vector_type(2)));

__device__ __forceinline__ float med3f(float a, float b, float c) {
    return __builtin_amdgcn_fmed3f(a, b, c);
}

__device__ __forceinline__ v2f fma2(v2f a, v2f b, v2f c) {
#if __has_builtin(__builtin_elementwise_fma)
    return __builtin_elementwise_fma(a, b, c);
#else
    v2f r; r.x = fmaf(a.x, b.x, c.x); r.y = fmaf(a.y, b.y, c.y); return r;
#endif
}

// ---------- kernel: prep (y pair-pack + W2 transpose) ----------
__global__ __launch_bounds__(256) void k_prep(const float* __restrict__ y,
                                              const float* __restrict__ w2,
                                              float4* __restrict__ ysp,
                                              float* __restrict__ w2t) {
    int idx = blockIdx.x * 256 + threadIdx.x;     // 40960 total
    if (idx < 8192) {                             // 8192 candidate-pairs
        int b = idx >> 12, q = idx & 4095;
        const float* p0 = y + (size_t)(b * M_CAND + 2 * q) * 3;
        float a0 = p0[0], a1 = p0[1], a2 = p0[2];
        float b0 = p0[3], b1 = p0[4], b2 = p0[5];
        float nwa = -(a0 * a0 + a1 * a1 + a2 * a2);
        float nwb = -(b0 * b0 + b1 * b1 + b2 * b2);
        float4* base = ysp + b * 8192;
        base[q]        = make_float4(a0, b0, a1, b1);   // plane A
        base[4096 + q] = make_float4(a2, b2, nwa, nwb); // plane B
    } else {
        int j = idx - 8192;                       // 32768 W2 elements
        int o = j >> 8, kk = j & 255;
        w2t[kk * 128 + o] = w2[j];
    }
}

// ---------- kernel: kNN top-20 by pd (one wave per row) ----------
__global__ __launch_bounds__(256, 4) void k_knn(const float* __restrict__ x,
                                                const float4* __restrict__ ysp,
                                                float* __restrict__ dfeat) {
    __shared__ float sm[4][64 * 21];              // per-wave region, stride 5 / 21
    const int wid  = threadIdx.x >> 6;
    const int lane = threadIdx.x & 63;
    const int row  = blockIdx.x * 4 + wid;        // grid 4096 -> rows 0..16383
    const int b    = row >> 13;
    const float x0 = x[row * 3 + 0];
    const float x1 = x[row * 3 + 1];
    const float x2 = x[row * 3 + 2];
    const v2f tx0p = {2.0f * x0, 2.0f * x0};
    const v2f tx1p = {2.0f * x1, 2.0f * x1};
    const v2f tx2p = {2.0f * x2, 2.0f * x2};
    const float xxn = -(x0 * x0 + x1 * x1 + x2 * x2);
    const v2f xxnp = {xxn, xxn};
    const float4* yb = ysp + b * 8192;            // plane A; plane B at +4096

    // descending per-lane top-4 of pd (largest pd = nearest)
    float bl[MPL];
#pragma unroll
    for (int j = 0; j < MPL; ++j) bl[j] = -3.0e38f;

#pragma unroll 2
    for (int t = 0; t < 16; ++t) {
        const float4* pa = yb + t * 256 + lane;
        const float4* pb = pa + 4096;
        float4 A[4], Bv[4];
        A[0]  = pa[0];  A[1]  = pa[64];  A[2]  = pa[128];  A[3]  = pa[192];
        Bv[0] = pb[0];  Bv[1] = pb[64];  Bv[2] = pb[128];  Bv[3] = pb[192];
#pragma unroll
        for (int i = 0; i < 4; ++i) {
            v2f y0p = {A[i].x,  A[i].y};
            v2f y1p = {A[i].z,  A[i].w};
            v2f y2p = {Bv[i].x, Bv[i].y};
            v2f nwp = {Bv[i].z, Bv[i].w};
            v2f pd = fma2(tx0p, y0p, fma2(tx1p, y1p, fma2(tx2p, y2p, xxnp))) + nwp;
            float va = pd.x, vb = pd.y;
#pragma unroll
            for (int jj = MPL - 1; jj >= 1; --jj) bl[jj] = med3f(va, bl[jj - 1], bl[jj]);
            bl[0] = fmaxf(bl[0], va);
#pragma unroll
            for (int jj = MPL - 1; jj >= 1; --jj) bl[jj] = med3f(vb, bl[jj - 1], bl[jj]);
            bl[0] = fmaxf(bl[0], vb);
        }
    }

    // cross-lane merge: 20 rounds of wave-max over per-lane sorted heads
    float* myp = sm[wid] + lane * (MPL + 1);      // stride 5: conflict-free
#pragma unroll
    for (int j = 0; j < MPL; ++j) myp[j] = bl[j];
    myp[MPL] = -3.0e38f;                          // pad slot
    asm volatile("s_waitcnt lgkmcnt(0)" ::: "memory");

    int ptr = 0;
    float sel = 0.0f;
    for (int r = 0; r < KSEL; ++r) {
        float head = myp[ptr];
        float mx = head;
#pragma unroll
        for (int off = 32; off >= 1; off >>= 1) mx = fmaxf(mx, __shfl_xor(mx, off, 64));
        unsigned long long ball = __ballot(head == mx);
        int winner = (int)__ffsll(ball) - 1;      // first lane holding max (tie-safe)
        ptr += (lane == winner) ? 1 : 0;
        if (lane == r) sel = mx;
    }

    // exactness guard: lane drained all 4 slots -> row may be wrong -> exact redo
    bool need_exact = (__ballot(ptr >= MPL) != 0ULL);
    if (need_exact) {
        float a[KSEL];
#pragma unroll
        for (int j = 0; j < KSEL; ++j) a[j] = -3.0e38f;
        for (int t = 0; t < 16; ++t) {
            const float4* pa = yb + t * 256 + lane;
            const float4* pb = pa + 4096;
            float4 A[4], Bv[4];
            A[0]  = pa[0];  A[1]  = pa[64];  A[2]  = pa[128];  A[3]  = pa[192];
            Bv[0] = pb[0];  Bv[1] = pb[64];  Bv[2] = pb[128];  Bv[3] = pb[192];
#pragma unroll
            for (int i = 0; i < 4; ++i) {
                v2f y0p = {A[i].x,  A[i].y};
                v2f y1p = {A[i].z,  A[i].w};
                v2f y2p = {Bv[i].x, Bv[i].y};
                v2f nwp = {Bv[i].z, Bv[i].w};
                v2f pd = fma2(tx0p, y0p, fma2(tx1p, y1p, fma2(tx2p, y2p, xxnp))) + nwp;
                float va = pd.x, vb = pd.y;
#pragma unroll
                for (int jj = KSEL - 1; jj >= 1; --jj) a[jj] = med3f(va, a[jj - 1], a[jj]);
                a[0] = fmaxf(a[0], va);
#pragma unroll
                for (int jj = KSEL - 1; jj >= 1; --jj) a[jj] = med3f(vb, a[jj - 1], a[jj]);
                a[0] = fmaxf(a[0], vb);
            }
        }
        float* mq = sm[wid] + lane * (KSEL + 1);  // stride 21
#pragma unroll
        for (int j = 0; j < KSEL; ++j) mq[j] = a[j];
        mq[KSEL] = -3.0e38f;
        asm volatile("s_waitcnt lgkmcnt(0)" ::: "memory");
        int ptr2 = 0;
        for (int r = 0; r < KSEL; ++r) {
            float head = mq[ptr2];
            float mx = head;
#pragma unroll
            for (int off = 32; off >= 1; off >>= 1) mx = fmaxf(mx, __shfl_xor(mx, off, 64));
            unsigned long long ball = __ballot(head == mx);
            int winner = (int)__ffsll(ball) - 1;
            ptr2 += (lane == winner) ? 1 : 0;
            if (lane == r) sel = mx;
        }
    }

    if (lane < KSEL) dfeat[row * KSEL + lane] = sel;
}

// ---------- kernel: layer 1 (20 -> 256) ----------
__global__ __launch_bounds__(256) void k_mlp1(const float* __restrict__ dfeat,
                                              const float* __restrict__ W1,
                                              const float* __restrict__ g1,
                                              const float* __restrict__ be1,
                                              const float* __restrict__ mu1,
                                              const float* __restrict__ va1,
                                              float* __restrict__ h1g) {
    const int o = threadIdx.x;                    // 0..255 = out channel
    const int rowbase = blockIdx.x * 16;          // grid 1024
    float w[KSEL];
#pragma unroll
    for (int j = 0; j < KSEL; j += 4) {
        float4 q = *(const float4*)(W1 + o * KSEL + j);
        w[j] = q.x; w[j + 1] = q.y; w[j + 2] = q.z; w[j + 3] = q.w;
    }
    const float s  = g1[o] * rsqrtf(va1[o] + 1e-5f);
    const float bc = be1[o] - mu1[o] * s;
#pragma unroll 4
    for (int r = 0; r < 16; ++r) {
        const float* dr = dfeat + (size_t)(rowbase + r) * KSEL;
        float dv[KSEL];
#pragma unroll
        for (int j = 0; j < KSEL; j += 4) {
            float4 q = *(const float4*)(dr + j);  // wave-uniform broadcast, L1-hot
            dv[j] = q.x; dv[j + 1] = q.y; dv[j + 2] = q.z; dv[j + 3] = q.w;
        }
        float acc0 = 0.f, acc1 = 0.f;
#pragma unroll
        for (int j = 0; j < KSEL; j += 2) {
            acc0 = fmaf(w[j], dv[j], acc0);
            acc1 = fmaf(w[j + 1], dv[j + 1], acc1);
        }
        float hv = fmaxf(0.f, fmaf(s, acc0 + acc1, bc));
        h1g[(size_t)(rowbase + r) * 256 + o] = hv;
    }
}

// ---------- kernel: layer 2 GEMM + bn2 + relu + W3 dot ----------
__global__ __launch_bounds__(256) void k_mlp2(const float* __restrict__ h1g,
                                              const float* __restrict__ W2T,
                                              const float* __restrict__ g2,
                                              const float* __restrict__ be2,
                                              const float* __restrict__ mu2,
                                              const float* __restrict__ va2,
                                              const float* __restrict__ W3,
                                              float* __restrict__ partial) {
    __shared__ float w2l[256 * 64];               // [k][oo] k-major
    const int t = threadIdx.x;
    const int ohalf = blockIdx.x & 1;             // grid 512
    const int rowbase = (blockIdx.x >> 1) * 64;
    const int obase = ohalf * 64;

    {
        const int oo4 = (t & 15) * 4;
        const int k0  = t >> 4;
        for (int i = 0; i < 16; ++i) {
            int k = k0 + 16 * i;
            float4 q = *(const float4*)(W2T + k * 128 + obase + oo4);
            *(float4*)(&w2l[k * 64 + oo4]) = q;
        }
    }
    __syncthreads();

    const int og = t & 15;
    const int rq = t >> 4;
    float acc[4][4];
#pragma unroll
    for (int r = 0; r < 4; ++r)
#pragma unroll
        for (int i = 0; i < 4; ++i) acc[r][i] = 0.f;

    const float* hrow = h1g + (size_t)(rowbase + rq * 4) * 256;
    for (int kq = 0; kq < 64; ++kq) {
        const int k = kq * 4;
        float4 hq[4];
        hq[0] = *(const float4*)(hrow + 0 * 256 + k);
        hq[1] = *(const float4*)(hrow + 1 * 256 + k);
        hq[2] = *(const float4*)(hrow + 2 * 256 + k);
        hq[3] = *(const float4*)(hrow + 3 * 256 + k);
        float4 wq[4];
        wq[0] = *(const float4*)(&w2l[(k + 0) * 64 + og * 4]);
        wq[1] = *(const float4*)(&w2l[(k + 1) * 64 + og * 4]);
        wq[2] = *(const float4*)(&w2l[(k + 2) * 64 + og * 4]);
        wq[3] = *(const float4*)(&w2l[(k + 3) * 64 + og * 4]);
#pragma unroll
        for (int r = 0; r < 4; ++r) {
            const float* hh = (const float*)&hq[r];
#pragma unroll
            for (int kk = 0; kk < 4; ++kk) {
                const float* ww = (const float*)&wq[kk];
                const float hval = hh[kk];
#pragma unroll
                for (int i = 0; i < 4; ++i)
                    acc[r][i] = fmaf(hval, ww[i], acc[r][i]);
            }
        }
    }

    float s2v[4], b2v[4], w3v[4];
#pragma unroll
    for (int i = 0; i < 4; ++i) {
        const int o = obase + og * 4 + i;
        const float sv = g2[o] * rsqrtf(va2[o] + 1e-5f);
        s2v[i] = sv;
        b2v[i] = be2[o] - mu2[o] * sv;
        w3v[i] = W3[o];
    }
#pragma unroll
    for (int r = 0; r < 4; ++r) {
        float c = 0.f;
#pragma unroll
        for (int i = 0; i < 4; ++i) {
            float h2 = fmaxf(0.f, fmaf(s2v[i], acc[r][i], b2v[i]));
            c = fmaf(w3v[i], h2, c);
        }
#pragma unroll
        for (int off = 8; off >= 1; off >>= 1) c += __shfl_xor(c, off, 64);
        if (og == 0) partial[ohalf * NROWS + rowbase + rq * 4 + r] = c;
    }
}

// ---------- kernel: combine halves + sigmoid ----------
__global__ __launch_bounds__(256) void k_out(const float* __restrict__ partial,
                                             float* __restrict__ out) {
    int i = blockIdx.x * 256 + threadIdx.x;       // grid 64 -> 16384
    float z = partial[i] + partial[NROWS + i];
    out[i] = 1.0f / (1.0f + expf(-z));
}

extern "C" void kernel_launch(void* const* d_in, const int* in_sizes, int n_in,
                              void* d_out, int out_size, void* d_ws, size_t ws_size,
                              hipStream_t stream) {
    const float* x   = (const float*)d_in[0];
    const float* y   = (const float*)d_in[1];
    const float* W1  = (const float*)d_in[2];
    const float* g1  = (const float*)d_in[3];
    const float* be1 = (const float*)d_in[4];
    const float* mu1 = (const float*)d_in[5];
    const float* va1 = (const float*)d_in[6];
    const float* W2  = (const float*)d_in[7];
    const float* g2  = (const float*)d_in[8];
    const float* be2 = (const float*)d_in[9];
    const float* mu2 = (const float*)d_in[10];
    const float* va2 = (const float*)d_in[11];
    const float* W3  = (const float*)d_in[12];
    float* out = (float*)d_out;

    char* ws = (char*)d_ws;
    float4* ysp  = (float4*)(ws);                                   // 262,144 B
    float* dfeat = (float*)(ws + 262144);                           // 1,310,720 B
    float* w2t   = (float*)(ws + 262144 + 1310720);                 // 131,072 B
    float* h1    = (float*)(ws + 262144 + 1310720 + 131072);        // 16,777,216 B
    float* part  = (float*)(ws + 262144 + 1310720 + 131072 + 16777216); // 131,072 B

    k_prep <<<160, 256, 0, stream>>>(y, W2, ysp, w2t);
    k_knn  <<<4096, 256, 0, stream>>>(x, ysp, dfeat);
    k_mlp1 <<<1024, 256, 0, stream>>>(dfeat, W1, g1, be1, mu1, va1, h1);
    k_mlp2 <<<512, 256, 0, stream>>>(h1, w2t, g2, be2, mu2, va2, W3, part);
    k_out  <<<64, 256, 0, stream>>>(part, out);
}